// Round 1
// 94.038 us; speedup vs baseline: 1.0386x; 1.0386x over previous
//
#include <hip/hip_runtime.h>
#include <math.h>

#define NB 64
#define NN 512
#define ND 128

typedef __attribute__((ext_vector_type(8))) short short8;
typedef __attribute__((ext_vector_type(4))) float f32x4;

// workspace layout (floats)
#define KVB_OFF   0                         // kv bf16: NB*NN*ND ushorts
#define QK_OFF    (NB*NN*ND/2)
#define QSUMP_OFF (QK_OFF + NB*NN)          // qsum partials: NB*4*ND floats

__device__ inline unsigned short f2bf(float x) {
    unsigned int u = __float_as_uint(x);
    return (unsigned short)((u + 0x7FFFu + ((u >> 16) & 1u)) >> 16);
}
__device__ inline float bf2f(unsigned short u) {
    return __uint_as_float(((unsigned int)u) << 16);
}

// K1: bf16 MFMA projection. 512 threads (8 waves), one 128-row tile per block.
// All three stages (aq, Wq, Wk) load in parallel into separate LDS buffers:
// single __syncthreads before compute (was 4 serial stage->sync chains).
// Each wave owns 16 q-cols + 16 k-cols (acc 64 VGPRs -> 2 waves/SIMD).
__global__ __launch_bounds__(512, 1) void proj_mfma(
    const float* __restrict__ aq, const float* __restrict__ mask,
    const float* __restrict__ Wq, const float* __restrict__ bq,
    const float* __restrict__ Wk, const float* __restrict__ bk,
    unsigned short* __restrict__ kvb, float* __restrict__ qk,
    float* __restrict__ qsum_part)
{
    __shared__ __align__(16) unsigned short wq_st[128][132];
    __shared__ __align__(16) unsigned short wk_st[128][132];
    __shared__ __align__(16) unsigned short ast[128][136];
    __shared__ float mask_lds[128];
    __shared__ float qk_part[8][128];

    const int b    = blockIdx.x >> 2;
    const int m0   = (blockIdx.x & 3) << 7;
    const int t    = threadIdx.x;
    const int w    = t >> 6, lane = t & 63;
    const int quad = lane >> 4, l16 = lane & 15;

    // ---- fused staging: aq tile + Wq + Wk, fp32 -> bf16 LDS, one sync ----
    {
        const float4* asrc = (const float4*)(aq + ((size_t)b*NN + m0)*ND);
        const float4* qsrc = (const float4*)Wq;
        const float4* ksrc = (const float4*)Wk;
        #pragma unroll
        for (int i = 0; i < 8; i++) {
            const int idx = t + 512*i;          // 4096 float4 per buffer
            const int row = idx >> 5, c4 = idx & 31;
            const float4 va = asrc[idx];
            const float4 vq = qsrc[idx];
            const float4 vk = ksrc[idx];
            ushort4 oa, oq, ok;
            oa.x = f2bf(va.x); oa.y = f2bf(va.y); oa.z = f2bf(va.z); oa.w = f2bf(va.w);
            oq.x = f2bf(vq.x); oq.y = f2bf(vq.y); oq.z = f2bf(vq.z); oq.w = f2bf(vq.w);
            ok.x = f2bf(vk.x); ok.y = f2bf(vk.y); ok.z = f2bf(vk.z); ok.w = f2bf(vk.w);
            *(ushort4*)&ast[row][c4*4]   = oa;
            *(ushort4*)&wq_st[row][c4*4] = oq;
            *(ushort4*)&wk_st[row][c4*4] = ok;
        }
        if (t < 128) mask_lds[t] = mask[b*NN + m0 + t];
    }
    __syncthreads();

    // ---- extract W fragments (this wave's 16 cols of Wq and of Wk) ----
    short8 bfr[2][4];
    {
        const int col = w*16 + l16;
        #pragma unroll
        for (int kc = 0; kc < 4; kc++) {
            short8 vq, vk;
            #pragma unroll
            for (int j = 0; j < 8; j++) {
                vq[j] = (short)wq_st[kc*32 + quad*8 + j][col];
                vk[j] = (short)wk_st[kc*32 + quad*8 + j][col];
            }
            bfr[0][kc] = vq;
            bfr[1][kc] = vk;
        }
    }

    f32x4 acc[8][2];
    #pragma unroll
    for (int m = 0; m < 8; m++) {
        acc[m][0] = (f32x4){0.f, 0.f, 0.f, 0.f};
        acc[m][1] = (f32x4){0.f, 0.f, 0.f, 0.f};
    }

    #pragma unroll
    for (int m = 0; m < 8; m++) {
        short8 afr[4];
        #pragma unroll
        for (int kc = 0; kc < 4; kc++)
            afr[kc] = *(const short8*)&ast[m*16 + l16][kc*32 + quad*8];
        #pragma unroll
        for (int nt = 0; nt < 2; nt++)
            #pragma unroll
            for (int kc = 0; kc < 4; kc++)
                acc[m][nt] = __builtin_amdgcn_mfma_f32_16x16x32_bf16(
                    afr[kc], bfr[nt][kc], acc[m][nt], 0, 0, 0);
    }

    // bias
    const float bvq = bq[w*16 + l16];
    const float bvk = bk[w*16 + l16];
    #pragma unroll
    for (int m = 0; m < 8; m++)
        #pragma unroll
        for (int r = 0; r < 4; r++) {
            acc[m][0][r] += bvq;
            acc[m][1][r] += bvk;
        }

    // store k rows as bf16 (C layout: row = m*16 + quad*4 + r, col = w*16 + l16)
    #pragma unroll
    for (int m = 0; m < 8; m++)
        #pragma unroll
        for (int r = 0; r < 4; r++) {
            const size_t row = (size_t)b*NN + m0 + m*16 + quad*4 + r;
            kvb[row*ND + w*16 + l16] = f2bf(acc[m][1][r]);
        }

    // qk partial: q.k over this wave's 16 d-cols (full fp32 precision)
    #pragma unroll
    for (int m = 0; m < 8; m++) {
        float p[4];
        #pragma unroll
        for (int r = 0; r < 4; r++)
            p[r] = acc[m][0][r] * acc[m][1][r];
        #pragma unroll
        for (int off = 1; off <= 8; off <<= 1)
            #pragma unroll
            for (int r = 0; r < 4; r++)
                p[r] += __shfl_xor(p[r], off);
        if (l16 == 0)
            #pragma unroll
            for (int r = 0; r < 4; r++)
                qk_part[w][m*16 + quad*4 + r] = p[r];
    }

    // qsum partial: disjoint slots, plain stores
    {
        float s0 = 0.f;
        #pragma unroll
        for (int m = 0; m < 8; m++)
            #pragma unroll
            for (int r = 0; r < 4; r++)
                s0 += mask_lds[m*16 + quad*4 + r] * acc[m][0][r];
        s0 += __shfl_xor(s0, 16);
        s0 += __shfl_xor(s0, 32);
        if (quad == 0)
            qsum_part[blockIdx.x * ND + w*16 + l16] = s0;
    }

    __syncthreads();
    if (t < 128)
        qk[(size_t)b*NN + m0 + t] =
            qk_part[0][t] + qk_part[1][t] + qk_part[2][t] + qk_part[3][t] +
            qk_part[4][t] + qk_part[5][t] + qk_part[6][t] + qk_part[7][t];
}

// K2: fused agg + norm + softmax + context. Grid: b*4 + cg, 512 threads.
__global__ __launch_bounds__(512) void fused_attn(
    const float* __restrict__ mask, const unsigned short* __restrict__ kvb,
    const float* __restrict__ qk, const float* __restrict__ qsum_part,
    float* __restrict__ out_attn, float* __restrict__ out_ctx)
{
    __shared__ float qs[128];
    __shared__ float mask_s[512];
    __shared__ float agg_s[512];          // then reused to hold e
    __shared__ float red[16];
    __shared__ float bc2[2];
    __shared__ float zred[8];
    __shared__ float zbc;
    __shared__ float ctx_part[64][36];    // 64 row-groups x 32 cols (pad 36)

    const int b  = blockIdx.x >> 2;
    const int cg = blockIdx.x & 3;
    const int t = threadIdx.x, w = t >> 6, lane = t & 63;
    const size_t rowbase = (size_t)b * NN;

    if (t < 128)
        qs[t] = qsum_part[(b*4 + 0)*ND + t] + qsum_part[(b*4 + 1)*ND + t]
              + qsum_part[(b*4 + 2)*ND + t] + qsum_part[(b*4 + 3)*ND + t];
    mask_s[t] = mask[rowbase + t];
    __syncthreads();

    // Phase A: agg[n]; 16 lanes per row (ushort8 = 8 d each), 4 rows/wave-pass
    const int h = lane & 15, quad = lane >> 4;
    float qsf[8];
    #pragma unroll
    for (int j = 0; j < 8; j++) qsf[j] = qs[h*8 + j];

    for (int i0 = 0; i0 < 64; i0 += 4) {
        const int n = w*64 + i0 + quad;
        const short8 kr = *(const short8*)(kvb + (rowbase + n)*ND + h*8);
        float p = 0.f;
        #pragma unroll
        for (int j = 0; j < 8; j++)
            p += bf2f((unsigned short)kr[j]) * qsf[j];
        #pragma unroll
        for (int off = 1; off <= 8; off <<= 1) p += __shfl_xor(p, off);
        if (h == 0)
            agg_s[n] = mask_s[n] * (p - qk[rowbase + n]);
    }
    __syncthreads();

    // Phase B: norm2 + masked max over 512 rows (thread t owns row t)
    const float v  = agg_s[t];
    const bool um  = mask_s[t] != 0.f;
    float sq = v * v;
    float mx = um ? v : -3.0e38f;
    #pragma unroll
    for (int off = 1; off <= 32; off <<= 1) {
        sq += __shfl_xor(sq, off);
        mx = fmaxf(mx, __shfl_xor(mx, off));
    }
    if (lane == 0) { red[w] = sq; red[8 + w] = mx; }
    __syncthreads();
    if (t == 0) {
        float s = 0.f, m = -3.0e38f;
        #pragma unroll
        for (int i = 0; i < 8; i++) { s += red[i]; m = fmaxf(m, red[8 + i]); }
        bc2[0] = sqrtf(s);
        bc2[1] = m;
    }
    __syncthreads();
    const float nrm = bc2[0];
    const float M   = bc2[1];

    // Phase C: masked exp + Z
    const float e = um ? expf((v - M) / nrm) : 0.f;
    float z = e;
    #pragma unroll
    for (int off = 1; off <= 32; off <<= 1) z += __shfl_xor(z, off);
    if (lane == 0) zred[w] = z;
    agg_s[t] = e;                 // own slot only
    __syncthreads();
    if (t == 0) {
        float s = 0.f;
        #pragma unroll
        for (int i = 0; i < 8; i++) s += zred[i];
        zbc = s;
    }
    __syncthreads();
    const float Z = zbc;
    if (cg == 0) out_attn[rowbase + t] = e / Z;

    // Phase D: context slice, cols [cg*32, cg*32+32); ushort4 loads, 8 iters
    const int c4  = (t & 7) * 4;         // 0,4,..,28 within slice
    const int col = cg*32 + c4;
    const int rg  = t >> 3;              // 64 row groups
    float a0 = 0.f, a1 = 0.f, a2 = 0.f, a3 = 0.f;
    for (int n = rg; n < NN; n += 64) {
        const ushort4 kk = *(const ushort4*)(kvb + (rowbase + n)*ND + col);
        const float ev = agg_s[n];
        a0 += ev * bf2f(kk.x);
        a1 += ev * bf2f(kk.y);
        a2 += ev * bf2f(kk.z);
        a3 += ev * bf2f(kk.w);
    }
    ctx_part[rg][c4]     = a0;
    ctx_part[rg][c4 + 1] = a1;
    ctx_part[rg][c4 + 2] = a2;
    ctx_part[rg][c4 + 3] = a3;
    __syncthreads();
    if (t < 32) {
        float s = 0.f;
        #pragma unroll
        for (int i = 0; i < 64; i++) s += ctx_part[i][t];
        out_ctx[(size_t)b*ND + cg*32 + t] = s / Z;
    }
}

extern "C" void kernel_launch(void* const* d_in, const int* in_sizes, int n_in,
                              void* d_out, int out_size, void* d_ws, size_t ws_size,
                              hipStream_t stream)
{
    const float* aq   = (const float*)d_in[0];
    const float* mask = (const float*)d_in[1];
    const float* Wq   = (const float*)d_in[2];
    const float* bq   = (const float*)d_in[3];
    const float* Wk   = (const float*)d_in[4];
    const float* bk   = (const float*)d_in[5];

    float* ws = (float*)d_ws;
    unsigned short* kvb       = (unsigned short*)(ws + KVB_OFF);
    float*          qk        = ws + QK_OFF;
    float*          qsum_part = ws + QSUMP_OFF;

    float* out_attn = (float*)d_out;
    float* out_ctx  = (float*)d_out + NB*NN;

    proj_mfma<<<dim3(256), dim3(512), 0, stream>>>(aq, mask, Wq, bq, Wk, bk,
                                                   kvb, qk, qsum_part);
    fused_attn<<<dim3(256), dim3(512), 0, stream>>>(mask, kvb, qk, qsum_part,
                                                    out_attn, out_ctx);
}